// Round 1
// baseline (610.220 us; speedup 1.0000x reference)
//
#include <hip/hip_runtime.h>

// GCN: 3x (A_hat X W + b, relu) -> mean-pool -> MLP.
// A_hat = D^-1/2 (A+I) D^-1/2.
// Layer1: x is [N,1] => A_hat(xW1) = (A_hat x) outer W1row  (scalar agg!)
// Layer2: agg(h1) in 64-d, then @W2 (64->128)
// Layer3: h2@W3 (128->64) first, then agg in 64-d

#define N_FEAT 64

__global__ void deg_kernel(const int* __restrict__ dst, float* __restrict__ deg, int E) {
    int e = blockIdx.x * blockDim.x + threadIdx.x;
    if (e < E) atomicAdd(&deg[dst[e]], 1.0f);
}

__global__ void dinv_kernel(const float* __restrict__ deg, float* __restrict__ dinv, int N) {
    int i = blockIdx.x * blockDim.x + threadIdx.x;
    if (i < N) dinv[i] = 1.0f / sqrtf(deg[i] + 1.0f);
}

// s_edge[v] += x[u] * dinv[u] * dinv[v]
__global__ void sagg_kernel(const int* __restrict__ src, const int* __restrict__ dst,
                            const float* __restrict__ x, const float* __restrict__ dinv,
                            float* __restrict__ s, int E) {
    int e = blockIdx.x * blockDim.x + threadIdx.x;
    if (e < E) {
        int u = src[e], v = dst[e];
        atomicAdd(&s[v], x[u] * dinv[u] * dinv[v]);
    }
}

// s[i] += x[i]*dinv[i]^2  (self loop)
__global__ void sfinal_kernel(const float* __restrict__ x, const float* __restrict__ dinv,
                              float* __restrict__ s, int N) {
    int i = blockIdx.x * blockDim.x + threadIdx.x;
    if (i < N) { float d = dinv[i]; s[i] += x[i] * d * d; }
}

// agg[i][j] = relu(s[i]*W1[j]+b1[j]) * dinv[i]^2   (self-loop term = accumulator init)
__global__ void init_agg1(const float* __restrict__ s, const float* __restrict__ dinv,
                          const float* __restrict__ W1, const float* __restrict__ b1,
                          float* __restrict__ agg, int N) {
    int g = blockIdx.x * blockDim.x + threadIdx.x;
    if (g < N * N_FEAT) {
        int i = g >> 6, j = g & 63;
        float d = dinv[i];
        float h = fmaxf(s[i] * W1[j] + b1[j], 0.0f);
        agg[g] = h * d * d;
    }
}

// wave-per-edge: agg[dst][lane] += relu(s[src]*W1[lane]+b1[lane]) * dinv[src]*dinv[dst]
__global__ void edge_agg1(const int* __restrict__ src, const int* __restrict__ dst,
                          const float* __restrict__ s, const float* __restrict__ dinv,
                          const float* __restrict__ W1, const float* __restrict__ b1,
                          float* __restrict__ agg, int E) {
    int e = blockIdx.x * 4 + (threadIdx.x >> 6);
    int lane = threadIdx.x & 63;
    if (e < E) {
        int u = src[e], v = dst[e];
        float w = dinv[u] * dinv[v];
        float h = fmaxf(s[u] * W1[lane] + b1[lane], 0.0f);
        atomicAdd(&agg[(size_t)v * N_FEAT + lane], h * w);
    }
}

// C = relu(A @ B + bias): A [M x 64], B [64 x 128]
__global__ __launch_bounds__(256) void gemm1(const float* __restrict__ A, const float* __restrict__ B,
                                             const float* __restrict__ bias, float* __restrict__ C, int M) {
    __shared__ float Bs[64 * 128];
    __shared__ float As[64 * 16];
    int tid = threadIdx.x;
    int row0 = blockIdx.x * 64;
    for (int idx = tid; idx < 64 * 128; idx += 256) Bs[idx] = B[idx];
    int c = (tid & 31) * 4;
    int rbase = (tid >> 5) * 8;
    float acc[8][4] = {};
    int lr = tid >> 2;
    int lk = (tid & 3) * 4;
    for (int kc = 0; kc < 64; kc += 16) {
        __syncthreads();
        float4 v = make_float4(0.f, 0.f, 0.f, 0.f);
        int grow = row0 + lr;
        if (grow < M) v = *(const float4*)&A[(size_t)grow * 64 + kc + lk];
        *(float4*)&As[lr * 16 + lk] = v;
        __syncthreads();
        #pragma unroll
        for (int k = 0; k < 16; ++k) {
            float4 b = *(const float4*)&Bs[(kc + k) * 128 + c];
            #pragma unroll
            for (int i = 0; i < 8; ++i) {
                float a = As[(rbase + i) * 16 + k];
                acc[i][0] += a * b.x; acc[i][1] += a * b.y;
                acc[i][2] += a * b.z; acc[i][3] += a * b.w;
            }
        }
    }
    float4 bv = *(const float4*)&bias[c];
    #pragma unroll
    for (int i = 0; i < 8; ++i) {
        int grow = row0 + rbase + i;
        if (grow < M) {
            float4 o;
            o.x = fmaxf(acc[i][0] + bv.x, 0.f);
            o.y = fmaxf(acc[i][1] + bv.y, 0.f);
            o.z = fmaxf(acc[i][2] + bv.z, 0.f);
            o.w = fmaxf(acc[i][3] + bv.w, 0.f);
            *(float4*)&C[(size_t)grow * 128 + c] = o;
        }
    }
}

// C = A @ B: A [M x 128], B [128 x 64], no bias/relu
__global__ __launch_bounds__(256) void gemm2(const float* __restrict__ A, const float* __restrict__ B,
                                             float* __restrict__ C, int M) {
    __shared__ float Bs[128 * 64];
    __shared__ float As[64 * 16];
    int tid = threadIdx.x;
    int row0 = blockIdx.x * 64;
    for (int idx = tid; idx < 128 * 64; idx += 256) Bs[idx] = B[idx];
    int c = (tid & 15) * 4;
    int rbase = (tid >> 4) * 4;
    float acc[4][4] = {};
    int lr = tid >> 2;
    int lk = (tid & 3) * 4;
    for (int kc = 0; kc < 128; kc += 16) {
        __syncthreads();
        float4 v = make_float4(0.f, 0.f, 0.f, 0.f);
        int grow = row0 + lr;
        if (grow < M) v = *(const float4*)&A[(size_t)grow * 128 + kc + lk];
        *(float4*)&As[lr * 16 + lk] = v;
        __syncthreads();
        #pragma unroll
        for (int k = 0; k < 16; ++k) {
            float4 b = *(const float4*)&Bs[(kc + k) * 64 + c];
            #pragma unroll
            for (int i = 0; i < 4; ++i) {
                float a = As[(rbase + i) * 16 + k];
                acc[i][0] += a * b.x; acc[i][1] += a * b.y;
                acc[i][2] += a * b.z; acc[i][3] += a * b.w;
            }
        }
    }
    #pragma unroll
    for (int i = 0; i < 4; ++i) {
        int grow = row0 + rbase + i;
        if (grow < M) {
            float4 o = make_float4(acc[i][0], acc[i][1], acc[i][2], acc[i][3]);
            *(float4*)&C[(size_t)grow * 64 + c] = o;
        }
    }
}

// agg[g] = m[g] * dinv[i]^2  (self-loop init for layer-3 aggregation)
__global__ void init_agg3(const float* __restrict__ m, const float* __restrict__ dinv,
                          float* __restrict__ agg, int N) {
    int g = blockIdx.x * blockDim.x + threadIdx.x;
    if (g < N * N_FEAT) {
        int i = g >> 6;
        float d = dinv[i];
        agg[g] = m[g] * d * d;
    }
}

// wave-per-edge: agg[dst][lane] += m[src][lane] * dinv[src]*dinv[dst]
__global__ void edge_agg3(const int* __restrict__ src, const int* __restrict__ dst,
                          const float* __restrict__ m, const float* __restrict__ dinv,
                          float* __restrict__ agg, int E) {
    int e = blockIdx.x * 4 + (threadIdx.x >> 6);
    int lane = threadIdx.x & 63;
    if (e < E) {
        int u = src[e], v = dst[e];
        float w = dinv[u] * dinv[v];
        float val = m[(size_t)u * N_FEAT + lane] * w;
        atomicAdd(&agg[(size_t)v * N_FEAT + lane], val);
    }
}

// h3 = relu(agg + b3); pooled[batch[i]] += h3; counts[batch[i]] += 1
__global__ void pool_kernel(const float* __restrict__ agg, const float* __restrict__ b3,
                            const int* __restrict__ batch, float* __restrict__ pooled,
                            float* __restrict__ counts, int N) {
    int i = blockIdx.x * 4 + (threadIdx.x >> 6);
    int lane = threadIdx.x & 63;
    if (i < N) {
        float h = fmaxf(agg[(size_t)i * N_FEAT + lane] + b3[lane], 0.0f);
        int g = batch[i];
        atomicAdd(&pooled[g * N_FEAT + lane], h);
        if (lane == 0) atomicAdd(&counts[g], 1.0f);
    }
}

// per-graph MLP: pooled/cnt -> relu(@lin1) -> @lin2
__global__ void mlp_kernel(const float* __restrict__ pooled, const float* __restrict__ counts,
                           const float* __restrict__ l1w, const float* __restrict__ l1b,
                           const float* __restrict__ l2w, const float* __restrict__ l2b,
                           float* __restrict__ out) {
    __shared__ float row[64];
    __shared__ float zs[32];
    int g = blockIdx.x;
    int l = threadIdx.x;
    float cnt = fmaxf(counts[g], 1.0f);
    row[l] = pooled[g * 64 + l] / cnt;
    __syncthreads();
    if (l < 32) {
        float z = l1b[l];
        #pragma unroll
        for (int k = 0; k < 64; ++k) z += row[k] * l1w[k * 32 + l];
        zs[l] = fmaxf(z, 0.0f);
    }
    __syncthreads();
    if (l == 0) {
        float o = l2b[0];
        #pragma unroll
        for (int j = 0; j < 32; ++j) o += zs[j] * l2w[j];
        out[g] = o;
    }
}

extern "C" void kernel_launch(void* const* d_in, const int* in_sizes, int n_in,
                              void* d_out, int out_size, void* d_ws, size_t ws_size,
                              hipStream_t stream) {
    const float* x   = (const float*)d_in[0];
    const float* W1  = (const float*)d_in[1];
    const float* b1  = (const float*)d_in[2];
    const float* W2  = (const float*)d_in[3];
    const float* b2  = (const float*)d_in[4];
    const float* W3  = (const float*)d_in[5];
    const float* b3  = (const float*)d_in[6];
    const float* l1w = (const float*)d_in[7];
    const float* l1b = (const float*)d_in[8];
    const float* l2w = (const float*)d_in[9];
    const float* l2b = (const float*)d_in[10];
    const int* ei    = (const int*)d_in[11];
    const int* batch = (const int*)d_in[12];

    int N = in_sizes[0];            // 50000
    int E = in_sizes[11] / 2;       // 600000
    int G = out_size;               // 256
    const int* src = ei;
    const int* dst = ei + E;

    float* ws = (float*)d_ws;
    float* deg    = ws;  ws += N;
    float* dinv   = ws;  ws += N;
    float* s      = ws;  ws += N;
    float* agg    = ws;  ws += (size_t)N * 64;    // reused: layer-2 agg, then layer-3 agg
    float* h2     = ws;  ws += (size_t)N * 128;
    float* m      = ws;  ws += (size_t)N * 64;
    float* pooled = ws;  ws += (size_t)G * 64;
    float* counts = ws;  ws += G;

    hipMemsetAsync(deg, 0, (size_t)N * sizeof(float), stream);
    hipMemsetAsync(s, 0, (size_t)N * sizeof(float), stream);
    hipMemsetAsync(pooled, 0, (size_t)(G * 64 + G) * sizeof(float), stream);

    int tb = 256;
    deg_kernel<<<(E + tb - 1) / tb, tb, 0, stream>>>(dst, deg, E);
    dinv_kernel<<<(N + tb - 1) / tb, tb, 0, stream>>>(deg, dinv, N);
    sagg_kernel<<<(E + tb - 1) / tb, tb, 0, stream>>>(src, dst, x, dinv, s, E);
    sfinal_kernel<<<(N + tb - 1) / tb, tb, 0, stream>>>(x, dinv, s, N);
    init_agg1<<<((size_t)N * 64 + tb - 1) / tb, tb, 0, stream>>>(s, dinv, W1, b1, agg, N);
    edge_agg1<<<(E + 3) / 4, tb, 0, stream>>>(src, dst, s, dinv, W1, b1, agg, E);
    gemm1<<<(N + 63) / 64, tb, 0, stream>>>(agg, W2, b2, h2, N);
    gemm2<<<(N + 63) / 64, tb, 0, stream>>>(h2, W3, m, N);
    init_agg3<<<((size_t)N * 64 + tb - 1) / tb, tb, 0, stream>>>(m, dinv, agg, N);
    edge_agg3<<<(E + 3) / 4, tb, 0, stream>>>(src, dst, m, dinv, agg, E);
    pool_kernel<<<(N + 3) / 4, tb, 0, stream>>>(agg, b3, batch, pooled, counts, N);
    mlp_kernel<<<G, 64, 0, stream>>>(pooled, counts, l1w, l1b, l2w, l2b, (float*)d_out);
}

// Round 2
// 516.540 us; speedup vs baseline: 1.1814x; 1.1814x over previous
//
#include <hip/hip_runtime.h>

// GCN: 3x (A_hat X W + b, relu) -> mean-pool -> MLP.
// A_hat = D^-1/2 (A+I) D^-1/2.
// Layer1: x is [N,1] => A_hat(xW1) = (A_hat x) outer W1row  (scalar agg!)
// Layer2: agg(h1) in 64-d, then @W2 (64->128)
// Layer3: h2@W3 (128->64) first, then agg in 64-d
// Pool: batch is SORTED -> segmented register accumulation, atomic only at
// graph boundaries (R1: was 50000 contended atomics/feature, 139us -> ~650 total)

#define N_FEAT 64
#define POOL_SUB 128

__global__ void deg_kernel(const int* __restrict__ dst, float* __restrict__ deg, int E) {
    int e = blockIdx.x * blockDim.x + threadIdx.x;
    if (e < E) atomicAdd(&deg[dst[e]], 1.0f);
}

__global__ void dinv_kernel(const float* __restrict__ deg, float* __restrict__ dinv, int N) {
    int i = blockIdx.x * blockDim.x + threadIdx.x;
    if (i < N) dinv[i] = 1.0f / sqrtf(deg[i] + 1.0f);
}

// s_edge[v] += x[u] * dinv[u] * dinv[v]
__global__ void sagg_kernel(const int* __restrict__ src, const int* __restrict__ dst,
                            const float* __restrict__ x, const float* __restrict__ dinv,
                            float* __restrict__ s, int E) {
    int e = blockIdx.x * blockDim.x + threadIdx.x;
    if (e < E) {
        int u = src[e], v = dst[e];
        atomicAdd(&s[v], x[u] * dinv[u] * dinv[v]);
    }
}

// s[i] += x[i]*dinv[i]^2  (self loop)
__global__ void sfinal_kernel(const float* __restrict__ x, const float* __restrict__ dinv,
                              float* __restrict__ s, int N) {
    int i = blockIdx.x * blockDim.x + threadIdx.x;
    if (i < N) { float d = dinv[i]; s[i] += x[i] * d * d; }
}

// agg[i][j] = relu(s[i]*W1[j]+b1[j]) * dinv[i]^2   (self-loop term = accumulator init)
__global__ void init_agg1(const float* __restrict__ s, const float* __restrict__ dinv,
                          const float* __restrict__ W1, const float* __restrict__ b1,
                          float* __restrict__ agg, int N) {
    int g = blockIdx.x * blockDim.x + threadIdx.x;
    if (g < N * N_FEAT) {
        int i = g >> 6, j = g & 63;
        float d = dinv[i];
        float h = fmaxf(s[i] * W1[j] + b1[j], 0.0f);
        agg[g] = h * d * d;
    }
}

// wave-per-edge: agg[dst][lane] += relu(s[src]*W1[lane]+b1[lane]) * dinv[src]*dinv[dst]
__global__ void edge_agg1(const int* __restrict__ src, const int* __restrict__ dst,
                          const float* __restrict__ s, const float* __restrict__ dinv,
                          const float* __restrict__ W1, const float* __restrict__ b1,
                          float* __restrict__ agg, int E) {
    int e = blockIdx.x * 4 + (threadIdx.x >> 6);
    int lane = threadIdx.x & 63;
    if (e < E) {
        int u = src[e], v = dst[e];
        float w = dinv[u] * dinv[v];
        float h = fmaxf(s[u] * W1[lane] + b1[lane], 0.0f);
        atomicAdd(&agg[(size_t)v * N_FEAT + lane], h * w);
    }
}

// C = relu(A @ B + bias): A [M x 64], B [64 x 128]
__global__ __launch_bounds__(256) void gemm1(const float* __restrict__ A, const float* __restrict__ B,
                                             const float* __restrict__ bias, float* __restrict__ C, int M) {
    __shared__ float Bs[64 * 128];
    __shared__ float As[64 * 16];
    int tid = threadIdx.x;
    int row0 = blockIdx.x * 64;
    for (int idx = tid; idx < 64 * 128; idx += 256) Bs[idx] = B[idx];
    int c = (tid & 31) * 4;
    int rbase = (tid >> 5) * 8;
    float acc[8][4] = {};
    int lr = tid >> 2;
    int lk = (tid & 3) * 4;
    for (int kc = 0; kc < 64; kc += 16) {
        __syncthreads();
        float4 v = make_float4(0.f, 0.f, 0.f, 0.f);
        int grow = row0 + lr;
        if (grow < M) v = *(const float4*)&A[(size_t)grow * 64 + kc + lk];
        *(float4*)&As[lr * 16 + lk] = v;
        __syncthreads();
        #pragma unroll
        for (int k = 0; k < 16; ++k) {
            float4 b = *(const float4*)&Bs[(kc + k) * 128 + c];
            #pragma unroll
            for (int i = 0; i < 8; ++i) {
                float a = As[(rbase + i) * 16 + k];
                acc[i][0] += a * b.x; acc[i][1] += a * b.y;
                acc[i][2] += a * b.z; acc[i][3] += a * b.w;
            }
        }
    }
    float4 bv = *(const float4*)&bias[c];
    #pragma unroll
    for (int i = 0; i < 8; ++i) {
        int grow = row0 + rbase + i;
        if (grow < M) {
            float4 o;
            o.x = fmaxf(acc[i][0] + bv.x, 0.f);
            o.y = fmaxf(acc[i][1] + bv.y, 0.f);
            o.z = fmaxf(acc[i][2] + bv.z, 0.f);
            o.w = fmaxf(acc[i][3] + bv.w, 0.f);
            *(float4*)&C[(size_t)grow * 128 + c] = o;
        }
    }
}

// C = A @ B: A [M x 128], B [128 x 64], no bias/relu
__global__ __launch_bounds__(256) void gemm2(const float* __restrict__ A, const float* __restrict__ B,
                                             float* __restrict__ C, int M) {
    __shared__ float Bs[128 * 64];
    __shared__ float As[64 * 16];
    int tid = threadIdx.x;
    int row0 = blockIdx.x * 64;
    for (int idx = tid; idx < 128 * 64; idx += 256) Bs[idx] = B[idx];
    int c = (tid & 15) * 4;
    int rbase = (tid >> 4) * 4;
    float acc[4][4] = {};
    int lr = tid >> 2;
    int lk = (tid & 3) * 4;
    for (int kc = 0; kc < 128; kc += 16) {
        __syncthreads();
        float4 v = make_float4(0.f, 0.f, 0.f, 0.f);
        int grow = row0 + lr;
        if (grow < M) v = *(const float4*)&A[(size_t)grow * 128 + kc + lk];
        *(float4*)&As[lr * 16 + lk] = v;
        __syncthreads();
        #pragma unroll
        for (int k = 0; k < 16; ++k) {
            float4 b = *(const float4*)&Bs[(kc + k) * 64 + c];
            #pragma unroll
            for (int i = 0; i < 4; ++i) {
                float a = As[(rbase + i) * 16 + k];
                acc[i][0] += a * b.x; acc[i][1] += a * b.y;
                acc[i][2] += a * b.z; acc[i][3] += a * b.w;
            }
        }
    }
    #pragma unroll
    for (int i = 0; i < 4; ++i) {
        int grow = row0 + rbase + i;
        if (grow < M) {
            float4 o = make_float4(acc[i][0], acc[i][1], acc[i][2], acc[i][3]);
            *(float4*)&C[(size_t)grow * 64 + c] = o;
        }
    }
}

// agg[g] = m[g] * dinv[i]^2  (self-loop init for layer-3 aggregation)
__global__ void init_agg3(const float* __restrict__ m, const float* __restrict__ dinv,
                          float* __restrict__ agg, int N) {
    int g = blockIdx.x * blockDim.x + threadIdx.x;
    if (g < N * N_FEAT) {
        int i = g >> 6;
        float d = dinv[i];
        agg[g] = m[g] * d * d;
    }
}

// wave-per-edge: agg[dst][lane] += m[src][lane] * dinv[src]*dinv[dst]
__global__ void edge_agg3(const int* __restrict__ src, const int* __restrict__ dst,
                          const float* __restrict__ m, const float* __restrict__ dinv,
                          float* __restrict__ agg, int E) {
    int e = blockIdx.x * 4 + (threadIdx.x >> 6);
    int lane = threadIdx.x & 63;
    if (e < E) {
        int u = src[e], v = dst[e];
        float w = dinv[u] * dinv[v];
        float val = m[(size_t)u * N_FEAT + lane] * w;
        atomicAdd(&agg[(size_t)v * N_FEAT + lane], val);
    }
}

// Segmented pool: batch is sorted. Each wave owns POOL_SUB consecutive nodes,
// accumulates h3=relu(agg+b3) per-lane in a register while the graph id is
// unchanged, flushes one atomic burst per boundary.
__global__ void pool_kernel(const float* __restrict__ agg, const float* __restrict__ b3,
                            const int* __restrict__ batch, float* __restrict__ pooled,
                            float* __restrict__ counts, int N) {
    int wave = (blockIdx.x * blockDim.x + threadIdx.x) >> 6;
    int lane = threadIdx.x & 63;
    int start = wave * POOL_SUB;
    if (start >= N) return;
    int end = min(start + POOL_SUB, N);
    float bl = b3[lane];
    int cur = batch[start];
    float acc = 0.0f;
    float cnt = 0.0f;
    for (int i = start; i < end; ++i) {
        int g = batch[i];
        if (g != cur) {
            atomicAdd(&pooled[cur * N_FEAT + lane], acc);
            if (lane == 0) atomicAdd(&counts[cur], cnt);
            acc = 0.0f; cnt = 0.0f; cur = g;
        }
        acc += fmaxf(agg[(size_t)i * N_FEAT + lane] + bl, 0.0f);
        cnt += 1.0f;
    }
    atomicAdd(&pooled[cur * N_FEAT + lane], acc);
    if (lane == 0) atomicAdd(&counts[cur], cnt);
}

// per-graph MLP: pooled/cnt -> relu(@lin1) -> @lin2
__global__ void mlp_kernel(const float* __restrict__ pooled, const float* __restrict__ counts,
                           const float* __restrict__ l1w, const float* __restrict__ l1b,
                           const float* __restrict__ l2w, const float* __restrict__ l2b,
                           float* __restrict__ out) {
    __shared__ float row[64];
    __shared__ float zs[32];
    int g = blockIdx.x;
    int l = threadIdx.x;
    float cnt = fmaxf(counts[g], 1.0f);
    row[l] = pooled[g * 64 + l] / cnt;
    __syncthreads();
    if (l < 32) {
        float z = l1b[l];
        #pragma unroll
        for (int k = 0; k < 64; ++k) z += row[k] * l1w[k * 32 + l];
        zs[l] = fmaxf(z, 0.0f);
    }
    __syncthreads();
    if (l == 0) {
        float o = l2b[0];
        #pragma unroll
        for (int j = 0; j < 32; ++j) o += zs[j] * l2w[j];
        out[g] = o;
    }
}

extern "C" void kernel_launch(void* const* d_in, const int* in_sizes, int n_in,
                              void* d_out, int out_size, void* d_ws, size_t ws_size,
                              hipStream_t stream) {
    const float* x   = (const float*)d_in[0];
    const float* W1  = (const float*)d_in[1];
    const float* b1  = (const float*)d_in[2];
    const float* W2  = (const float*)d_in[3];
    const float* b2  = (const float*)d_in[4];
    const float* W3  = (const float*)d_in[5];
    const float* b3  = (const float*)d_in[6];
    const float* l1w = (const float*)d_in[7];
    const float* l1b = (const float*)d_in[8];
    const float* l2w = (const float*)d_in[9];
    const float* l2b = (const float*)d_in[10];
    const int* ei    = (const int*)d_in[11];
    const int* batch = (const int*)d_in[12];

    int N = in_sizes[0];            // 50000
    int E = in_sizes[11] / 2;       // 600000
    int G = out_size;               // 256
    const int* src = ei;
    const int* dst = ei + E;

    float* ws = (float*)d_ws;
    float* deg    = ws;  ws += N;
    float* dinv   = ws;  ws += N;
    float* s      = ws;  ws += N;
    float* agg    = ws;  ws += (size_t)N * 64;    // reused: layer-2 agg, then layer-3 agg
    float* h2     = ws;  ws += (size_t)N * 128;
    float* m      = ws;  ws += (size_t)N * 64;
    float* pooled = ws;  ws += (size_t)G * 64;
    float* counts = ws;  ws += G;

    hipMemsetAsync(deg, 0, (size_t)N * sizeof(float), stream);
    hipMemsetAsync(s, 0, (size_t)N * sizeof(float), stream);
    hipMemsetAsync(pooled, 0, (size_t)(G * 64 + G) * sizeof(float), stream);

    int tb = 256;
    deg_kernel<<<(E + tb - 1) / tb, tb, 0, stream>>>(dst, deg, E);
    dinv_kernel<<<(N + tb - 1) / tb, tb, 0, stream>>>(deg, dinv, N);
    sagg_kernel<<<(E + tb - 1) / tb, tb, 0, stream>>>(src, dst, x, dinv, s, E);
    sfinal_kernel<<<(N + tb - 1) / tb, tb, 0, stream>>>(x, dinv, s, N);
    init_agg1<<<((size_t)N * 64 + tb - 1) / tb, tb, 0, stream>>>(s, dinv, W1, b1, agg, N);
    edge_agg1<<<(E + 3) / 4, tb, 0, stream>>>(src, dst, s, dinv, W1, b1, agg, E);
    gemm1<<<(N + 63) / 64, tb, 0, stream>>>(agg, W2, b2, h2, N);
    gemm2<<<(N + 63) / 64, tb, 0, stream>>>(h2, W3, m, N);
    init_agg3<<<((size_t)N * 64 + tb - 1) / tb, tb, 0, stream>>>(m, dinv, agg, N);
    edge_agg3<<<(E + 3) / 4, tb, 0, stream>>>(src, dst, m, dinv, agg, E);
    int pool_waves = (N + POOL_SUB - 1) / POOL_SUB;
    pool_kernel<<<(pool_waves + 3) / 4, tb, 0, stream>>>(agg, b3, batch, pooled, counts, N);
    mlp_kernel<<<G, 64, 0, stream>>>(pooled, counts, l1w, l1b, l2w, l2b, (float*)d_out);
}

// Round 3
// 427.220 us; speedup vs baseline: 1.4284x; 1.2091x over previous
//
#include <hip/hip_runtime.h>

// GCN: 3x (A_hat X W + b, relu) -> mean-pool -> MLP.  A_hat = D^-1/2 (A+I) D^-1/2.
// Layer1: x is [N,1] => A_hat(xW1) = (A_hat x) outer W1row  (scalar agg)
// Layer2: agg in 64-d then @W2; Layer3: @W3 (128->64) then agg in 64-d.
// R2->R3: scatter-atomics (150 MB atomic RMW stream, 2x128us) replaced by
// CSR-by-dst build + wave-per-node register gather (no atomics on agg).

#define N_FEAT 64
#define POOL_SUB 128
#define SCAN_T 1024

__global__ void degi_kernel(const int* __restrict__ dst, int* __restrict__ deg, int E) {
    int e = blockIdx.x * blockDim.x + threadIdx.x;
    if (e < E) atomicAdd(&deg[dst[e]], 1);
}

__global__ void dinv_kernel(const int* __restrict__ deg, float* __restrict__ dinv, int N) {
    int i = blockIdx.x * blockDim.x + threadIdx.x;
    if (i < N) dinv[i] = rsqrtf((float)deg[i] + 1.0f);
}

// One workgroup exclusive scan over deg -> rowstart[N+1]; cursor = rowstart copy.
__global__ __launch_bounds__(SCAN_T) void scan_kernel(const int* __restrict__ deg,
                                                      int* __restrict__ rowstart,
                                                      int* __restrict__ cursor, int N) {
    __shared__ int sdata[SCAN_T];
    int t = threadIdx.x;
    int chunk = (N + SCAN_T - 1) / SCAN_T;
    int lo = t * chunk, hi = min(lo + chunk, N);
    int partial = 0;
    for (int i = lo; i < hi; ++i) partial += deg[i];
    sdata[t] = partial;
    __syncthreads();
    for (int st = 1; st < SCAN_T; st <<= 1) {
        int v = (t >= st) ? sdata[t - st] : 0;
        __syncthreads();
        sdata[t] += v;
        __syncthreads();
    }
    int running = sdata[t] - partial;  // exclusive offset
    for (int i = lo; i < hi; ++i) {
        rowstart[i] = running;
        cursor[i] = running;
        running += deg[i];
    }
    if (t == 0) rowstart[N] = sdata[SCAN_T - 1];
}

// csr_src[pos] = src[e], pos allocated per-dst via cursor atomics
__global__ void fill_kernel(const int* __restrict__ src, const int* __restrict__ dst,
                            int* __restrict__ cursor, int* __restrict__ csr, int E) {
    int e = blockIdx.x * blockDim.x + threadIdx.x;
    if (e < E) {
        int pos = atomicAdd(&cursor[dst[e]], 1);
        csr[pos] = src[e];
    }
}

// s[v] = dinv[v] * sum_{u->v} x[u]*dinv[u] + x[v]*dinv[v]^2   (thread per node)
__global__ void sagg_gather(const int* __restrict__ rowstart, const int* __restrict__ csr,
                            const float* __restrict__ x, const float* __restrict__ dinv,
                            float* __restrict__ s, int N) {
    int v = blockIdx.x * blockDim.x + threadIdx.x;
    if (v >= N) return;
    int rs = rowstart[v], re = rowstart[v + 1];
    float sum = 0.0f;
    for (int e = rs; e < re; ++e) {
        int u = csr[e];
        sum += x[u] * dinv[u];
    }
    float dv = dinv[v];
    s[v] = dv * sum + x[v] * dv * dv;
}

// Layer-2 aggregation of h1 (h1[i][j] = relu(s[i]*W1[j]+b1[j]), never materialized).
// wave-per-node: agg[v][j] = dinv[v]*sum_{u->v} h1[u][j]*dinv[u] + h1[v][j]*dinv[v]^2
__global__ void agg1_gather(const int* __restrict__ rowstart, const int* __restrict__ csr,
                            const float* __restrict__ s, const float* __restrict__ dinv,
                            const float* __restrict__ W1, const float* __restrict__ b1,
                            float* __restrict__ agg, int N) {
    int v = blockIdx.x * 4 + (threadIdx.x >> 6);
    int lane = threadIdx.x & 63;
    if (v >= N) return;
    float w1 = W1[lane], bb = b1[lane];
    int rs = rowstart[v], re = rowstart[v + 1];
    float acc = 0.0f;
    int e = rs;
    for (; e + 1 < re; e += 2) {
        int u0 = csr[e], u1 = csr[e + 1];
        float d0 = dinv[u0], s0 = s[u0];
        float d1 = dinv[u1], s1 = s[u1];
        acc += fmaxf(s0 * w1 + bb, 0.0f) * d0;
        acc += fmaxf(s1 * w1 + bb, 0.0f) * d1;
    }
    if (e < re) {
        int u = csr[e];
        acc += fmaxf(s[u] * w1 + bb, 0.0f) * dinv[u];
    }
    float dv = dinv[v];
    agg[(size_t)v * N_FEAT + lane] = dv * acc + fmaxf(s[v] * w1 + bb, 0.0f) * dv * dv;
}

// C = relu(A @ B + bias): A [M x 64], B [64 x 128]
__global__ __launch_bounds__(256) void gemm1(const float* __restrict__ A, const float* __restrict__ B,
                                             const float* __restrict__ bias, float* __restrict__ C, int M) {
    __shared__ float Bs[64 * 128];
    __shared__ float As[64 * 16];
    int tid = threadIdx.x;
    int row0 = blockIdx.x * 64;
    for (int idx = tid; idx < 64 * 128; idx += 256) Bs[idx] = B[idx];
    int c = (tid & 31) * 4;
    int rbase = (tid >> 5) * 8;
    float acc[8][4] = {};
    int lr = tid >> 2;
    int lk = (tid & 3) * 4;
    for (int kc = 0; kc < 64; kc += 16) {
        __syncthreads();
        float4 v = make_float4(0.f, 0.f, 0.f, 0.f);
        int grow = row0 + lr;
        if (grow < M) v = *(const float4*)&A[(size_t)grow * 64 + kc + lk];
        *(float4*)&As[lr * 16 + lk] = v;
        __syncthreads();
        #pragma unroll
        for (int k = 0; k < 16; ++k) {
            float4 b = *(const float4*)&Bs[(kc + k) * 128 + c];
            #pragma unroll
            for (int i = 0; i < 8; ++i) {
                float a = As[(rbase + i) * 16 + k];
                acc[i][0] += a * b.x; acc[i][1] += a * b.y;
                acc[i][2] += a * b.z; acc[i][3] += a * b.w;
            }
        }
    }
    float4 bv = *(const float4*)&bias[c];
    #pragma unroll
    for (int i = 0; i < 8; ++i) {
        int grow = row0 + rbase + i;
        if (grow < M) {
            float4 o;
            o.x = fmaxf(acc[i][0] + bv.x, 0.f);
            o.y = fmaxf(acc[i][1] + bv.y, 0.f);
            o.z = fmaxf(acc[i][2] + bv.z, 0.f);
            o.w = fmaxf(acc[i][3] + bv.w, 0.f);
            *(float4*)&C[(size_t)grow * 128 + c] = o;
        }
    }
}

// C = A @ B: A [M x 128], B [128 x 64]
__global__ __launch_bounds__(256) void gemm2(const float* __restrict__ A, const float* __restrict__ B,
                                             float* __restrict__ C, int M) {
    __shared__ float Bs[128 * 64];
    __shared__ float As[64 * 16];
    int tid = threadIdx.x;
    int row0 = blockIdx.x * 64;
    for (int idx = tid; idx < 128 * 64; idx += 256) Bs[idx] = B[idx];
    int c = (tid & 15) * 4;
    int rbase = (tid >> 4) * 4;
    float acc[4][4] = {};
    int lr = tid >> 2;
    int lk = (tid & 3) * 4;
    for (int kc = 0; kc < 128; kc += 16) {
        __syncthreads();
        float4 v = make_float4(0.f, 0.f, 0.f, 0.f);
        int grow = row0 + lr;
        if (grow < M) v = *(const float4*)&A[(size_t)grow * 128 + kc + lk];
        *(float4*)&As[lr * 16 + lk] = v;
        __syncthreads();
        #pragma unroll
        for (int k = 0; k < 16; ++k) {
            float4 b = *(const float4*)&Bs[(kc + k) * 64 + c];
            #pragma unroll
            for (int i = 0; i < 4; ++i) {
                float a = As[(rbase + i) * 16 + k];
                acc[i][0] += a * b.x; acc[i][1] += a * b.y;
                acc[i][2] += a * b.z; acc[i][3] += a * b.w;
            }
        }
    }
    #pragma unroll
    for (int i = 0; i < 4; ++i) {
        int grow = row0 + rbase + i;
        if (grow < M) {
            float4 o = make_float4(acc[i][0], acc[i][1], acc[i][2], acc[i][3]);
            *(float4*)&C[(size_t)grow * 64 + c] = o;
        }
    }
}

// Layer-3 aggregation of m = h2@W3. wave-per-node:
// agg[v][j] = dinv[v]*sum_{u->v} m[u][j]*dinv[u] + m[v][j]*dinv[v]^2
__global__ void agg3_gather(const int* __restrict__ rowstart, const int* __restrict__ csr,
                            const float* __restrict__ m, const float* __restrict__ dinv,
                            float* __restrict__ agg, int N) {
    int v = blockIdx.x * 4 + (threadIdx.x >> 6);
    int lane = threadIdx.x & 63;
    if (v >= N) return;
    int rs = rowstart[v], re = rowstart[v + 1];
    float acc = 0.0f;
    int e = rs;
    for (; e + 1 < re; e += 2) {
        int u0 = csr[e], u1 = csr[e + 1];
        float d0 = dinv[u0], d1 = dinv[u1];
        float m0 = m[(size_t)u0 * N_FEAT + lane];
        float m1 = m[(size_t)u1 * N_FEAT + lane];
        acc += m0 * d0 + m1 * d1;
    }
    if (e < re) {
        int u = csr[e];
        acc += m[(size_t)u * N_FEAT + lane] * dinv[u];
    }
    float dv = dinv[v];
    agg[(size_t)v * N_FEAT + lane] = dv * acc + m[(size_t)v * N_FEAT + lane] * dv * dv;
}

// Segmented pool over sorted batch: register accumulation, atomic per boundary.
__global__ void pool_kernel(const float* __restrict__ agg, const float* __restrict__ b3,
                            const int* __restrict__ batch, float* __restrict__ pooled,
                            float* __restrict__ counts, int N) {
    int wave = (blockIdx.x * blockDim.x + threadIdx.x) >> 6;
    int lane = threadIdx.x & 63;
    int start = wave * POOL_SUB;
    if (start >= N) return;
    int end = min(start + POOL_SUB, N);
    float bl = b3[lane];
    int cur = batch[start];
    float acc = 0.0f;
    float cnt = 0.0f;
    for (int i = start; i < end; ++i) {
        int g = batch[i];
        if (g != cur) {
            atomicAdd(&pooled[cur * N_FEAT + lane], acc);
            if (lane == 0) atomicAdd(&counts[cur], cnt);
            acc = 0.0f; cnt = 0.0f; cur = g;
        }
        acc += fmaxf(agg[(size_t)i * N_FEAT + lane] + bl, 0.0f);
        cnt += 1.0f;
    }
    atomicAdd(&pooled[cur * N_FEAT + lane], acc);
    if (lane == 0) atomicAdd(&counts[cur], cnt);
}

// per-graph MLP: pooled/cnt -> relu(@lin1) -> @lin2
__global__ void mlp_kernel(const float* __restrict__ pooled, const float* __restrict__ counts,
                           const float* __restrict__ l1w, const float* __restrict__ l1b,
                           const float* __restrict__ l2w, const float* __restrict__ l2b,
                           float* __restrict__ out) {
    __shared__ float row[64];
    __shared__ float zs[32];
    int g = blockIdx.x;
    int l = threadIdx.x;
    float cnt = fmaxf(counts[g], 1.0f);
    row[l] = pooled[g * 64 + l] / cnt;
    __syncthreads();
    if (l < 32) {
        float z = l1b[l];
        #pragma unroll
        for (int k = 0; k < 64; ++k) z += row[k] * l1w[k * 32 + l];
        zs[l] = fmaxf(z, 0.0f);
    }
    __syncthreads();
    if (l == 0) {
        float o = l2b[0];
        #pragma unroll
        for (int j = 0; j < 32; ++j) o += zs[j] * l2w[j];
        out[g] = o;
    }
}

extern "C" void kernel_launch(void* const* d_in, const int* in_sizes, int n_in,
                              void* d_out, int out_size, void* d_ws, size_t ws_size,
                              hipStream_t stream) {
    const float* x   = (const float*)d_in[0];
    const float* W1  = (const float*)d_in[1];
    const float* b1  = (const float*)d_in[2];
    const float* W2  = (const float*)d_in[3];
    const float* b2  = (const float*)d_in[4];
    const float* W3  = (const float*)d_in[5];
    const float* b3  = (const float*)d_in[6];
    const float* l1w = (const float*)d_in[7];
    const float* l1b = (const float*)d_in[8];
    const float* l2w = (const float*)d_in[9];
    const float* l2b = (const float*)d_in[10];
    const int* ei    = (const int*)d_in[11];
    const int* batch = (const int*)d_in[12];

    int N = in_sizes[0];            // 50000
    int E = in_sizes[11] / 2;       // 600000
    int G = out_size;               // 256
    const int* src = ei;
    const int* dst = ei + E;

    char* wsb = (char*)d_ws;
    int*   deg      = (int*)wsb;                 wsb += (size_t)N * 4;
    int*   rowstart = (int*)wsb;                 wsb += (size_t)(N + 1) * 4;
    int*   cursor   = (int*)wsb;                 wsb += (size_t)N * 4;
    int*   csr      = (int*)wsb;                 wsb += (size_t)E * 4;
    float* dinv     = (float*)wsb;               wsb += (size_t)N * 4;
    float* s        = (float*)wsb;               wsb += (size_t)N * 4;
    float* agg      = (float*)wsb;               wsb += (size_t)N * 64 * 4;  // layer2 agg, reused for layer3
    float* h2       = (float*)wsb;               wsb += (size_t)N * 128 * 4;
    float* m        = (float*)wsb;               wsb += (size_t)N * 64 * 4;
    float* pooled   = (float*)wsb;               wsb += (size_t)G * 64 * 4;
    float* counts   = (float*)wsb;               wsb += (size_t)G * 4;

    hipMemsetAsync(deg, 0, (size_t)N * sizeof(int), stream);
    hipMemsetAsync(pooled, 0, (size_t)(G * 64 + G) * sizeof(float), stream);

    int tb = 256;
    degi_kernel<<<(E + tb - 1) / tb, tb, 0, stream>>>(dst, deg, E);
    dinv_kernel<<<(N + tb - 1) / tb, tb, 0, stream>>>(deg, dinv, N);
    scan_kernel<<<1, SCAN_T, 0, stream>>>(deg, rowstart, cursor, N);
    fill_kernel<<<(E + tb - 1) / tb, tb, 0, stream>>>(src, dst, cursor, csr, E);
    sagg_gather<<<(N + tb - 1) / tb, tb, 0, stream>>>(rowstart, csr, x, dinv, s, N);
    agg1_gather<<<(N + 3) / 4, tb, 0, stream>>>(rowstart, csr, s, dinv, W1, b1, agg, N);
    gemm1<<<(N + 63) / 64, tb, 0, stream>>>(agg, W2, b2, h2, N);
    gemm2<<<(N + 63) / 64, tb, 0, stream>>>(h2, W3, m, N);
    agg3_gather<<<(N + 3) / 4, tb, 0, stream>>>(rowstart, csr, m, dinv, agg, N);
    int pool_waves = (N + POOL_SUB - 1) / POOL_SUB;
    pool_kernel<<<(pool_waves + 3) / 4, tb, 0, stream>>>(agg, b3, batch, pooled, counts, N);
    mlp_kernel<<<G, 64, 0, stream>>>(pooled, counts, l1w, l1b, l2w, l2b, (float*)d_out);
}

// Round 4
// 326.074 us; speedup vs baseline: 1.8714x; 1.3102x over previous
//
#include <hip/hip_runtime.h>

// GCN: 3x (A_hat X W + b, relu) -> mean-pool -> MLP.  A_hat = D^-1/2 (A+I) D^-1/2.
// Layer1: x is [N,1] => A_hat(xW1) = (A_hat x) outer W1row  (scalar agg)
// Layer2: agg in 64-d then @W2; Layer3: @W3 (128->64) then agg in 64-d.
// R3: CSR-by-dst + wave-per-node gather (no agg atomics).
// R3->R4: single-workgroup scan (110us, 0.14% occupancy) -> 3-phase
// hierarchical scan (bsum / bscan / rscan), all coalesced, device-wide.

#define N_FEAT 64
#define POOL_SUB 128
#define SCAN_CHUNK 1024   // elements per scan block; NB = ceil(N/1024) must be <= 64

__global__ void degi_kernel(const int* __restrict__ dst, int* __restrict__ deg, int E) {
    int e = blockIdx.x * blockDim.x + threadIdx.x;
    if (e < E) atomicAdd(&deg[dst[e]], 1);
}

__global__ void dinv_kernel(const int* __restrict__ deg, float* __restrict__ dinv, int N) {
    int i = blockIdx.x * blockDim.x + threadIdx.x;
    if (i < N) dinv[i] = rsqrtf((float)deg[i] + 1.0f);
}

// Phase 1: per-block sum of SCAN_CHUNK deg entries
__global__ __launch_bounds__(256) void bsum_kernel(const int* __restrict__ deg,
                                                   int* __restrict__ bsum, int N) {
    __shared__ int red[256];
    int b = blockIdx.x, t = threadIdx.x;
    int base = b * SCAN_CHUNK;
    int sum = 0;
    #pragma unroll
    for (int j = 0; j < SCAN_CHUNK / 256; ++j) {
        int idx = base + j * 256 + t;
        if (idx < N) sum += deg[idx];
    }
    red[t] = sum;
    __syncthreads();
    if (t < 64) {
        int s2 = red[t] + red[t + 64] + red[t + 128] + red[t + 192];
        #pragma unroll
        for (int off = 32; off; off >>= 1) s2 += __shfl_down(s2, off);
        if (t == 0) bsum[b] = s2;
    }
}

// Phase 2: one wave exclusive-scans the <=64 block sums in place
__global__ void bscan_kernel(int* __restrict__ bsum, int NB) {
    int t = threadIdx.x;  // 64
    int orig = (t < NB) ? bsum[t] : 0;
    int v = orig;
    #pragma unroll
    for (int off = 1; off < 64; off <<= 1) {
        int w = __shfl_up(v, off);
        if (t >= off) v += w;
    }
    if (t < NB) bsum[t] = v - orig;  // exclusive offset
}

// Phase 3: per-block local scan + global offset -> rowstart, cursor
__global__ __launch_bounds__(256) void rscan_kernel(const int* __restrict__ deg,
                                                    const int* __restrict__ boff,
                                                    int* __restrict__ rowstart,
                                                    int* __restrict__ cursor, int N, int NB) {
    __shared__ int tsum[256];
    int b = blockIdx.x, t = threadIdx.x;
    int base = b * SCAN_CHUNK + t * 4;
    int d[4];
    int s = 0;
    #pragma unroll
    for (int j = 0; j < 4; ++j) {
        int idx = base + j;
        d[j] = (idx < N) ? deg[idx] : 0;
        s += d[j];
    }
    tsum[t] = s;
    __syncthreads();
    for (int off = 1; off < 256; off <<= 1) {
        int v = (t >= off) ? tsum[t - off] : 0;
        __syncthreads();
        tsum[t] += v;
        __syncthreads();
    }
    int run = boff[b] + tsum[t] - s;  // exclusive prefix before this thread
    #pragma unroll
    for (int j = 0; j < 4; ++j) {
        int idx = base + j;
        if (idx < N) { rowstart[idx] = run; cursor[idx] = run; }
        run += d[j];
    }
    if (b == NB - 1 && t == 255) rowstart[N] = run;
}

// csr_src[pos] = src[e], pos allocated per-dst via cursor atomics
__global__ void fill_kernel(const int* __restrict__ src, const int* __restrict__ dst,
                            int* __restrict__ cursor, int* __restrict__ csr, int E) {
    int e = blockIdx.x * blockDim.x + threadIdx.x;
    if (e < E) {
        int pos = atomicAdd(&cursor[dst[e]], 1);
        csr[pos] = src[e];
    }
}

// s[v] = dinv[v] * sum_{u->v} x[u]*dinv[u] + x[v]*dinv[v]^2   (thread per node)
__global__ void sagg_gather(const int* __restrict__ rowstart, const int* __restrict__ csr,
                            const float* __restrict__ x, const float* __restrict__ dinv,
                            float* __restrict__ s, int N) {
    int v = blockIdx.x * blockDim.x + threadIdx.x;
    if (v >= N) return;
    int rs = rowstart[v], re = rowstart[v + 1];
    float sum = 0.0f;
    for (int e = rs; e < re; ++e) {
        int u = csr[e];
        sum += x[u] * dinv[u];
    }
    float dv = dinv[v];
    s[v] = dv * sum + x[v] * dv * dv;
}

// Layer-2 aggregation of h1 (h1[i][j] = relu(s[i]*W1[j]+b1[j]), never materialized).
// wave-per-node: agg[v][j] = dinv[v]*sum_{u->v} h1[u][j]*dinv[u] + h1[v][j]*dinv[v]^2
__global__ void agg1_gather(const int* __restrict__ rowstart, const int* __restrict__ csr,
                            const float* __restrict__ s, const float* __restrict__ dinv,
                            const float* __restrict__ W1, const float* __restrict__ b1,
                            float* __restrict__ agg, int N) {
    int v = blockIdx.x * 4 + (threadIdx.x >> 6);
    int lane = threadIdx.x & 63;
    if (v >= N) return;
    float w1 = W1[lane], bb = b1[lane];
    int rs = rowstart[v], re = rowstart[v + 1];
    float acc = 0.0f;
    int e = rs;
    for (; e + 1 < re; e += 2) {
        int u0 = csr[e], u1 = csr[e + 1];
        float d0 = dinv[u0], s0 = s[u0];
        float d1 = dinv[u1], s1 = s[u1];
        acc += fmaxf(s0 * w1 + bb, 0.0f) * d0;
        acc += fmaxf(s1 * w1 + bb, 0.0f) * d1;
    }
    if (e < re) {
        int u = csr[e];
        acc += fmaxf(s[u] * w1 + bb, 0.0f) * dinv[u];
    }
    float dv = dinv[v];
    agg[(size_t)v * N_FEAT + lane] = dv * acc + fmaxf(s[v] * w1 + bb, 0.0f) * dv * dv;
}

// C = relu(A @ B + bias): A [M x 64], B [64 x 128]
__global__ __launch_bounds__(256) void gemm1(const float* __restrict__ A, const float* __restrict__ B,
                                             const float* __restrict__ bias, float* __restrict__ C, int M) {
    __shared__ float Bs[64 * 128];
    __shared__ float As[64 * 16];
    int tid = threadIdx.x;
    int row0 = blockIdx.x * 64;
    for (int idx = tid; idx < 64 * 128; idx += 256) Bs[idx] = B[idx];
    int c = (tid & 31) * 4;
    int rbase = (tid >> 5) * 8;
    float acc[8][4] = {};
    int lr = tid >> 2;
    int lk = (tid & 3) * 4;
    for (int kc = 0; kc < 64; kc += 16) {
        __syncthreads();
        float4 v = make_float4(0.f, 0.f, 0.f, 0.f);
        int grow = row0 + lr;
        if (grow < M) v = *(const float4*)&A[(size_t)grow * 64 + kc + lk];
        *(float4*)&As[lr * 16 + lk] = v;
        __syncthreads();
        #pragma unroll
        for (int k = 0; k < 16; ++k) {
            float4 b = *(const float4*)&Bs[(kc + k) * 128 + c];
            #pragma unroll
            for (int i = 0; i < 8; ++i) {
                float a = As[(rbase + i) * 16 + k];
                acc[i][0] += a * b.x; acc[i][1] += a * b.y;
                acc[i][2] += a * b.z; acc[i][3] += a * b.w;
            }
        }
    }
    float4 bv = *(const float4*)&bias[c];
    #pragma unroll
    for (int i = 0; i < 8; ++i) {
        int grow = row0 + rbase + i;
        if (grow < M) {
            float4 o;
            o.x = fmaxf(acc[i][0] + bv.x, 0.f);
            o.y = fmaxf(acc[i][1] + bv.y, 0.f);
            o.z = fmaxf(acc[i][2] + bv.z, 0.f);
            o.w = fmaxf(acc[i][3] + bv.w, 0.f);
            *(float4*)&C[(size_t)grow * 128 + c] = o;
        }
    }
}

// C = A @ B: A [M x 128], B [128 x 64]
__global__ __launch_bounds__(256) void gemm2(const float* __restrict__ A, const float* __restrict__ B,
                                             float* __restrict__ C, int M) {
    __shared__ float Bs[128 * 64];
    __shared__ float As[64 * 16];
    int tid = threadIdx.x;
    int row0 = blockIdx.x * 64;
    for (int idx = tid; idx < 128 * 64; idx += 256) Bs[idx] = B[idx];
    int c = (tid & 15) * 4;
    int rbase = (tid >> 4) * 4;
    float acc[4][4] = {};
    int lr = tid >> 2;
    int lk = (tid & 3) * 4;
    for (int kc = 0; kc < 128; kc += 16) {
        __syncthreads();
        float4 v = make_float4(0.f, 0.f, 0.f, 0.f);
        int grow = row0 + lr;
        if (grow < M) v = *(const float4*)&A[(size_t)grow * 128 + kc + lk];
        *(float4*)&As[lr * 16 + lk] = v;
        __syncthreads();
        #pragma unroll
        for (int k = 0; k < 16; ++k) {
            float4 b = *(const float4*)&Bs[(kc + k) * 64 + c];
            #pragma unroll
            for (int i = 0; i < 4; ++i) {
                float a = As[(rbase + i) * 16 + k];
                acc[i][0] += a * b.x; acc[i][1] += a * b.y;
                acc[i][2] += a * b.z; acc[i][3] += a * b.w;
            }
        }
    }
    #pragma unroll
    for (int i = 0; i < 4; ++i) {
        int grow = row0 + rbase + i;
        if (grow < M) {
            float4 o = make_float4(acc[i][0], acc[i][1], acc[i][2], acc[i][3]);
            *(float4*)&C[(size_t)grow * 64 + c] = o;
        }
    }
}

// Layer-3 aggregation of m = h2@W3. wave-per-node:
// agg[v][j] = dinv[v]*sum_{u->v} m[u][j]*dinv[u] + m[v][j]*dinv[v]^2
__global__ void agg3_gather(const int* __restrict__ rowstart, const int* __restrict__ csr,
                            const float* __restrict__ m, const float* __restrict__ dinv,
                            float* __restrict__ agg, int N) {
    int v = blockIdx.x * 4 + (threadIdx.x >> 6);
    int lane = threadIdx.x & 63;
    if (v >= N) return;
    int rs = rowstart[v], re = rowstart[v + 1];
    float acc = 0.0f;
    int e = rs;
    for (; e + 1 < re; e += 2) {
        int u0 = csr[e], u1 = csr[e + 1];
        float d0 = dinv[u0], d1 = dinv[u1];
        float m0 = m[(size_t)u0 * N_FEAT + lane];
        float m1 = m[(size_t)u1 * N_FEAT + lane];
        acc += m0 * d0 + m1 * d1;
    }
    if (e < re) {
        int u = csr[e];
        acc += m[(size_t)u * N_FEAT + lane] * dinv[u];
    }
    float dv = dinv[v];
    agg[(size_t)v * N_FEAT + lane] = dv * acc + m[(size_t)v * N_FEAT + lane] * dv * dv;
}

// Segmented pool over sorted batch: register accumulation, atomic per boundary.
__global__ void pool_kernel(const float* __restrict__ agg, const float* __restrict__ b3,
                            const int* __restrict__ batch, float* __restrict__ pooled,
                            float* __restrict__ counts, int N) {
    int wave = (blockIdx.x * blockDim.x + threadIdx.x) >> 6;
    int lane = threadIdx.x & 63;
    int start = wave * POOL_SUB;
    if (start >= N) return;
    int end = min(start + POOL_SUB, N);
    float bl = b3[lane];
    int cur = batch[start];
    float acc = 0.0f;
    float cnt = 0.0f;
    for (int i = start; i < end; ++i) {
        int g = batch[i];
        if (g != cur) {
            atomicAdd(&pooled[cur * N_FEAT + lane], acc);
            if (lane == 0) atomicAdd(&counts[cur], cnt);
            acc = 0.0f; cnt = 0.0f; cur = g;
        }
        acc += fmaxf(agg[(size_t)i * N_FEAT + lane] + bl, 0.0f);
        cnt += 1.0f;
    }
    atomicAdd(&pooled[cur * N_FEAT + lane], acc);
    if (lane == 0) atomicAdd(&counts[cur], cnt);
}

// per-graph MLP: pooled/cnt -> relu(@lin1) -> @lin2
__global__ void mlp_kernel(const float* __restrict__ pooled, const float* __restrict__ counts,
                           const float* __restrict__ l1w, const float* __restrict__ l1b,
                           const float* __restrict__ l2w, const float* __restrict__ l2b,
                           float* __restrict__ out) {
    __shared__ float row[64];
    __shared__ float zs[32];
    int g = blockIdx.x;
    int l = threadIdx.x;
    float cnt = fmaxf(counts[g], 1.0f);
    row[l] = pooled[g * 64 + l] / cnt;
    __syncthreads();
    if (l < 32) {
        float z = l1b[l];
        #pragma unroll
        for (int k = 0; k < 64; ++k) z += row[k] * l1w[k * 32 + l];
        zs[l] = fmaxf(z, 0.0f);
    }
    __syncthreads();
    if (l == 0) {
        float o = l2b[0];
        #pragma unroll
        for (int j = 0; j < 32; ++j) o += zs[j] * l2w[j];
        out[g] = o;
    }
}

extern "C" void kernel_launch(void* const* d_in, const int* in_sizes, int n_in,
                              void* d_out, int out_size, void* d_ws, size_t ws_size,
                              hipStream_t stream) {
    const float* x   = (const float*)d_in[0];
    const float* W1  = (const float*)d_in[1];
    const float* b1  = (const float*)d_in[2];
    const float* W2  = (const float*)d_in[3];
    const float* b2  = (const float*)d_in[4];
    const float* W3  = (const float*)d_in[5];
    const float* b3  = (const float*)d_in[6];
    const float* l1w = (const float*)d_in[7];
    const float* l1b = (const float*)d_in[8];
    const float* l2w = (const float*)d_in[9];
    const float* l2b = (const float*)d_in[10];
    const int* ei    = (const int*)d_in[11];
    const int* batch = (const int*)d_in[12];

    int N = in_sizes[0];            // 50000
    int E = in_sizes[11] / 2;       // 600000
    int G = out_size;               // 256
    const int* src = ei;
    const int* dst = ei + E;

    char* wsb = (char*)d_ws;
    int*   deg      = (int*)wsb;                 wsb += (size_t)N * 4;
    int*   rowstart = (int*)wsb;                 wsb += (size_t)(N + 1) * 4;
    int*   cursor   = (int*)wsb;                 wsb += (size_t)N * 4;
    int*   bsum     = (int*)wsb;                 wsb += 64 * 4;
    int*   csr      = (int*)wsb;                 wsb += (size_t)E * 4;
    float* dinv     = (float*)wsb;               wsb += (size_t)N * 4;
    float* s        = (float*)wsb;               wsb += (size_t)N * 4;
    float* agg      = (float*)wsb;               wsb += (size_t)N * 64 * 4;  // layer2 agg, reused for layer3
    float* h2       = (float*)wsb;               wsb += (size_t)N * 128 * 4;
    float* m        = (float*)wsb;               wsb += (size_t)N * 64 * 4;
    float* pooled   = (float*)wsb;               wsb += (size_t)G * 64 * 4;
    float* counts   = (float*)wsb;               wsb += (size_t)G * 4;

    hipMemsetAsync(deg, 0, (size_t)N * sizeof(int), stream);
    hipMemsetAsync(pooled, 0, (size_t)(G * 64 + G) * sizeof(float), stream);

    int tb = 256;
    int NB = (N + SCAN_CHUNK - 1) / SCAN_CHUNK;   // 49 for N=50000 (must be <= 64)
    degi_kernel<<<(E + tb - 1) / tb, tb, 0, stream>>>(dst, deg, E);
    dinv_kernel<<<(N + tb - 1) / tb, tb, 0, stream>>>(deg, dinv, N);
    bsum_kernel<<<NB, 256, 0, stream>>>(deg, bsum, N);
    bscan_kernel<<<1, 64, 0, stream>>>(bsum, NB);
    rscan_kernel<<<NB, 256, 0, stream>>>(deg, bsum, rowstart, cursor, N, NB);
    fill_kernel<<<(E + tb - 1) / tb, tb, 0, stream>>>(src, dst, cursor, csr, E);
    sagg_gather<<<(N + tb - 1) / tb, tb, 0, stream>>>(rowstart, csr, x, dinv, s, N);
    agg1_gather<<<(N + 3) / 4, tb, 0, stream>>>(rowstart, csr, s, dinv, W1, b1, agg, N);
    gemm1<<<(N + 63) / 64, tb, 0, stream>>>(agg, W2, b2, h2, N);
    gemm2<<<(N + 63) / 64, tb, 0, stream>>>(h2, W3, m, N);
    agg3_gather<<<(N + 3) / 4, tb, 0, stream>>>(rowstart, csr, m, dinv, agg, N);
    int pool_waves = (N + POOL_SUB - 1) / POOL_SUB;
    pool_kernel<<<(pool_waves + 3) / 4, tb, 0, stream>>>(agg, b3, batch, pooled, counts, N);
    mlp_kernel<<<G, 64, 0, stream>>>(pooled, counts, l1w, l1b, l2w, l2b, (float*)d_out);
}

// Round 5
// 294.216 us; speedup vs baseline: 2.0741x; 1.1083x over previous
//
#include <hip/hip_runtime.h>

// GCN: 3x (A_hat X W + b, relu) -> mean-pool -> MLP.  A_hat = D^-1/2 (A+I) D^-1/2.
// Layer1: x is [N,1] => A_hat(xW1) = (A_hat x) outer W1row  (scalar agg)
// Layer2: agg in 64-d then @W2; Layer3: @W3 (128->64) then agg in 64-d.
// R3: CSR-by-dst + wave-per-node gather (no agg atomics).
// R4: hierarchical scan (bsum/bscan/rscan).
// R4->R5: pool POOL_SUB 128->16 (391 waves @3% occ, latency-bound 48us ->
// 3125 waves; atomic bursts ~650->~3400, still negligible on 64KB table).

#define N_FEAT 64
#define POOL_SUB 16
#define SCAN_CHUNK 1024   // elements per scan block; NB = ceil(N/1024) must be <= 64

__global__ void degi_kernel(const int* __restrict__ dst, int* __restrict__ deg, int E) {
    int e = blockIdx.x * blockDim.x + threadIdx.x;
    if (e < E) atomicAdd(&deg[dst[e]], 1);
}

__global__ void dinv_kernel(const int* __restrict__ deg, float* __restrict__ dinv, int N) {
    int i = blockIdx.x * blockDim.x + threadIdx.x;
    if (i < N) dinv[i] = rsqrtf((float)deg[i] + 1.0f);
}

// Phase 1: per-block sum of SCAN_CHUNK deg entries
__global__ __launch_bounds__(256) void bsum_kernel(const int* __restrict__ deg,
                                                   int* __restrict__ bsum, int N) {
    __shared__ int red[256];
    int b = blockIdx.x, t = threadIdx.x;
    int base = b * SCAN_CHUNK;
    int sum = 0;
    #pragma unroll
    for (int j = 0; j < SCAN_CHUNK / 256; ++j) {
        int idx = base + j * 256 + t;
        if (idx < N) sum += deg[idx];
    }
    red[t] = sum;
    __syncthreads();
    if (t < 64) {
        int s2 = red[t] + red[t + 64] + red[t + 128] + red[t + 192];
        #pragma unroll
        for (int off = 32; off; off >>= 1) s2 += __shfl_down(s2, off);
        if (t == 0) bsum[b] = s2;
    }
}

// Phase 2: one wave exclusive-scans the <=64 block sums in place
__global__ void bscan_kernel(int* __restrict__ bsum, int NB) {
    int t = threadIdx.x;  // 64
    int orig = (t < NB) ? bsum[t] : 0;
    int v = orig;
    #pragma unroll
    for (int off = 1; off < 64; off <<= 1) {
        int w = __shfl_up(v, off);
        if (t >= off) v += w;
    }
    if (t < NB) bsum[t] = v - orig;  // exclusive offset
}

// Phase 3: per-block local scan + global offset -> rowstart, cursor
__global__ __launch_bounds__(256) void rscan_kernel(const int* __restrict__ deg,
                                                    const int* __restrict__ boff,
                                                    int* __restrict__ rowstart,
                                                    int* __restrict__ cursor, int N, int NB) {
    __shared__ int tsum[256];
    int b = blockIdx.x, t = threadIdx.x;
    int base = b * SCAN_CHUNK + t * 4;
    int d[4];
    int s = 0;
    #pragma unroll
    for (int j = 0; j < 4; ++j) {
        int idx = base + j;
        d[j] = (idx < N) ? deg[idx] : 0;
        s += d[j];
    }
    tsum[t] = s;
    __syncthreads();
    for (int off = 1; off < 256; off <<= 1) {
        int v = (t >= off) ? tsum[t - off] : 0;
        __syncthreads();
        tsum[t] += v;
        __syncthreads();
    }
    int run = boff[b] + tsum[t] - s;  // exclusive prefix before this thread
    #pragma unroll
    for (int j = 0; j < 4; ++j) {
        int idx = base + j;
        if (idx < N) { rowstart[idx] = run; cursor[idx] = run; }
        run += d[j];
    }
    if (b == NB - 1 && t == 255) rowstart[N] = run;
}

// csr_src[pos] = src[e], pos allocated per-dst via cursor atomics
__global__ void fill_kernel(const int* __restrict__ src, const int* __restrict__ dst,
                            int* __restrict__ cursor, int* __restrict__ csr, int E) {
    int e = blockIdx.x * blockDim.x + threadIdx.x;
    if (e < E) {
        int pos = atomicAdd(&cursor[dst[e]], 1);
        csr[pos] = src[e];
    }
}

// s[v] = dinv[v] * sum_{u->v} x[u]*dinv[u] + x[v]*dinv[v]^2   (thread per node)
__global__ void sagg_gather(const int* __restrict__ rowstart, const int* __restrict__ csr,
                            const float* __restrict__ x, const float* __restrict__ dinv,
                            float* __restrict__ s, int N) {
    int v = blockIdx.x * blockDim.x + threadIdx.x;
    if (v >= N) return;
    int rs = rowstart[v], re = rowstart[v + 1];
    float sum = 0.0f;
    for (int e = rs; e < re; ++e) {
        int u = csr[e];
        sum += x[u] * dinv[u];
    }
    float dv = dinv[v];
    s[v] = dv * sum + x[v] * dv * dv;
}

// Layer-2 aggregation of h1 (h1[i][j] = relu(s[i]*W1[j]+b1[j]), never materialized).
// wave-per-node: agg[v][j] = dinv[v]*sum_{u->v} h1[u][j]*dinv[u] + h1[v][j]*dinv[v]^2
__global__ void agg1_gather(const int* __restrict__ rowstart, const int* __restrict__ csr,
                            const float* __restrict__ s, const float* __restrict__ dinv,
                            const float* __restrict__ W1, const float* __restrict__ b1,
                            float* __restrict__ agg, int N) {
    int v = blockIdx.x * 4 + (threadIdx.x >> 6);
    int lane = threadIdx.x & 63;
    if (v >= N) return;
    float w1 = W1[lane], bb = b1[lane];
    int rs = rowstart[v], re = rowstart[v + 1];
    float acc = 0.0f;
    int e = rs;
    for (; e + 1 < re; e += 2) {
        int u0 = csr[e], u1 = csr[e + 1];
        float d0 = dinv[u0], s0 = s[u0];
        float d1 = dinv[u1], s1 = s[u1];
        acc += fmaxf(s0 * w1 + bb, 0.0f) * d0;
        acc += fmaxf(s1 * w1 + bb, 0.0f) * d1;
    }
    if (e < re) {
        int u = csr[e];
        acc += fmaxf(s[u] * w1 + bb, 0.0f) * dinv[u];
    }
    float dv = dinv[v];
    agg[(size_t)v * N_FEAT + lane] = dv * acc + fmaxf(s[v] * w1 + bb, 0.0f) * dv * dv;
}

// C = relu(A @ B + bias): A [M x 64], B [64 x 128]
__global__ __launch_bounds__(256) void gemm1(const float* __restrict__ A, const float* __restrict__ B,
                                             const float* __restrict__ bias, float* __restrict__ C, int M) {
    __shared__ float Bs[64 * 128];
    __shared__ float As[64 * 16];
    int tid = threadIdx.x;
    int row0 = blockIdx.x * 64;
    for (int idx = tid; idx < 64 * 128; idx += 256) Bs[idx] = B[idx];
    int c = (tid & 31) * 4;
    int rbase = (tid >> 5) * 8;
    float acc[8][4] = {};
    int lr = tid >> 2;
    int lk = (tid & 3) * 4;
    for (int kc = 0; kc < 64; kc += 16) {
        __syncthreads();
        float4 v = make_float4(0.f, 0.f, 0.f, 0.f);
        int grow = row0 + lr;
        if (grow < M) v = *(const float4*)&A[(size_t)grow * 64 + kc + lk];
        *(float4*)&As[lr * 16 + lk] = v;
        __syncthreads();
        #pragma unroll
        for (int k = 0; k < 16; ++k) {
            float4 b = *(const float4*)&Bs[(kc + k) * 128 + c];
            #pragma unroll
            for (int i = 0; i < 8; ++i) {
                float a = As[(rbase + i) * 16 + k];
                acc[i][0] += a * b.x; acc[i][1] += a * b.y;
                acc[i][2] += a * b.z; acc[i][3] += a * b.w;
            }
        }
    }
    float4 bv = *(const float4*)&bias[c];
    #pragma unroll
    for (int i = 0; i < 8; ++i) {
        int grow = row0 + rbase + i;
        if (grow < M) {
            float4 o;
            o.x = fmaxf(acc[i][0] + bv.x, 0.f);
            o.y = fmaxf(acc[i][1] + bv.y, 0.f);
            o.z = fmaxf(acc[i][2] + bv.z, 0.f);
            o.w = fmaxf(acc[i][3] + bv.w, 0.f);
            *(float4*)&C[(size_t)grow * 128 + c] = o;
        }
    }
}

// C = A @ B: A [M x 128], B [128 x 64]
__global__ __launch_bounds__(256) void gemm2(const float* __restrict__ A, const float* __restrict__ B,
                                             float* __restrict__ C, int M) {
    __shared__ float Bs[128 * 64];
    __shared__ float As[64 * 16];
    int tid = threadIdx.x;
    int row0 = blockIdx.x * 64;
    for (int idx = tid; idx < 128 * 64; idx += 256) Bs[idx] = B[idx];
    int c = (tid & 15) * 4;
    int rbase = (tid >> 4) * 4;
    float acc[4][4] = {};
    int lr = tid >> 2;
    int lk = (tid & 3) * 4;
    for (int kc = 0; kc < 128; kc += 16) {
        __syncthreads();
        float4 v = make_float4(0.f, 0.f, 0.f, 0.f);
        int grow = row0 + lr;
        if (grow < M) v = *(const float4*)&A[(size_t)grow * 128 + kc + lk];
        *(float4*)&As[lr * 16 + lk] = v;
        __syncthreads();
        #pragma unroll
        for (int k = 0; k < 16; ++k) {
            float4 b = *(const float4*)&Bs[(kc + k) * 64 + c];
            #pragma unroll
            for (int i = 0; i < 4; ++i) {
                float a = As[(rbase + i) * 16 + k];
                acc[i][0] += a * b.x; acc[i][1] += a * b.y;
                acc[i][2] += a * b.z; acc[i][3] += a * b.w;
            }
        }
    }
    #pragma unroll
    for (int i = 0; i < 4; ++i) {
        int grow = row0 + rbase + i;
        if (grow < M) {
            float4 o = make_float4(acc[i][0], acc[i][1], acc[i][2], acc[i][3]);
            *(float4*)&C[(size_t)grow * 64 + c] = o;
        }
    }
}

// Layer-3 aggregation of m = h2@W3. wave-per-node:
// agg[v][j] = dinv[v]*sum_{u->v} m[u][j]*dinv[u] + m[v][j]*dinv[v]^2
__global__ void agg3_gather(const int* __restrict__ rowstart, const int* __restrict__ csr,
                            const float* __restrict__ m, const float* __restrict__ dinv,
                            float* __restrict__ agg, int N) {
    int v = blockIdx.x * 4 + (threadIdx.x >> 6);
    int lane = threadIdx.x & 63;
    if (v >= N) return;
    int rs = rowstart[v], re = rowstart[v + 1];
    float acc = 0.0f;
    int e = rs;
    for (; e + 1 < re; e += 2) {
        int u0 = csr[e], u1 = csr[e + 1];
        float d0 = dinv[u0], d1 = dinv[u1];
        float m0 = m[(size_t)u0 * N_FEAT + lane];
        float m1 = m[(size_t)u1 * N_FEAT + lane];
        acc += m0 * d0 + m1 * d1;
    }
    if (e < re) {
        int u = csr[e];
        acc += m[(size_t)u * N_FEAT + lane] * dinv[u];
    }
    float dv = dinv[v];
    agg[(size_t)v * N_FEAT + lane] = dv * acc + m[(size_t)v * N_FEAT + lane] * dv * dv;
}

// Segmented pool over sorted batch: register accumulation, atomic per boundary.
// POOL_SUB=16: 3125 waves (~12/CU) hides load latency; was 128 -> 391 waves, 3% occ.
__global__ void pool_kernel(const float* __restrict__ agg, const float* __restrict__ b3,
                            const int* __restrict__ batch, float* __restrict__ pooled,
                            float* __restrict__ counts, int N) {
    int wave = (blockIdx.x * blockDim.x + threadIdx.x) >> 6;
    int lane = threadIdx.x & 63;
    int start = wave * POOL_SUB;
    if (start >= N) return;
    int end = min(start + POOL_SUB, N);
    float bl = b3[lane];
    int cur = batch[start];
    float acc = 0.0f;
    float cnt = 0.0f;
    for (int i = start; i < end; ++i) {
        int g = batch[i];
        if (g != cur) {
            atomicAdd(&pooled[cur * N_FEAT + lane], acc);
            if (lane == 0) atomicAdd(&counts[cur], cnt);
            acc = 0.0f; cnt = 0.0f; cur = g;
        }
        acc += fmaxf(agg[(size_t)i * N_FEAT + lane] + bl, 0.0f);
        cnt += 1.0f;
    }
    atomicAdd(&pooled[cur * N_FEAT + lane], acc);
    if (lane == 0) atomicAdd(&counts[cur], cnt);
}

// per-graph MLP: pooled/cnt -> relu(@lin1) -> @lin2
__global__ void mlp_kernel(const float* __restrict__ pooled, const float* __restrict__ counts,
                           const float* __restrict__ l1w, const float* __restrict__ l1b,
                           const float* __restrict__ l2w, const float* __restrict__ l2b,
                           float* __restrict__ out) {
    __shared__ float row[64];
    __shared__ float zs[32];
    int g = blockIdx.x;
    int l = threadIdx.x;
    float cnt = fmaxf(counts[g], 1.0f);
    row[l] = pooled[g * 64 + l] / cnt;
    __syncthreads();
    if (l < 32) {
        float z = l1b[l];
        #pragma unroll
        for (int k = 0; k < 64; ++k) z += row[k] * l1w[k * 32 + l];
        zs[l] = fmaxf(z, 0.0f);
    }
    __syncthreads();
    if (l == 0) {
        float o = l2b[0];
        #pragma unroll
        for (int j = 0; j < 32; ++j) o += zs[j] * l2w[j];
        out[g] = o;
    }
}

extern "C" void kernel_launch(void* const* d_in, const int* in_sizes, int n_in,
                              void* d_out, int out_size, void* d_ws, size_t ws_size,
                              hipStream_t stream) {
    const float* x   = (const float*)d_in[0];
    const float* W1  = (const float*)d_in[1];
    const float* b1  = (const float*)d_in[2];
    const float* W2  = (const float*)d_in[3];
    const float* b2  = (const float*)d_in[4];
    const float* W3  = (const float*)d_in[5];
    const float* b3  = (const float*)d_in[6];
    const float* l1w = (const float*)d_in[7];
    const float* l1b = (const float*)d_in[8];
    const float* l2w = (const float*)d_in[9];
    const float* l2b = (const float*)d_in[10];
    const int* ei    = (const int*)d_in[11];
    const int* batch = (const int*)d_in[12];

    int N = in_sizes[0];            // 50000
    int E = in_sizes[11] / 2;       // 600000
    int G = out_size;               // 256
    const int* src = ei;
    const int* dst = ei + E;

    char* wsb = (char*)d_ws;
    int*   deg      = (int*)wsb;                 wsb += (size_t)N * 4;
    int*   rowstart = (int*)wsb;                 wsb += (size_t)(N + 1) * 4;
    int*   cursor   = (int*)wsb;                 wsb += (size_t)N * 4;
    int*   bsum     = (int*)wsb;                 wsb += 64 * 4;
    int*   csr      = (int*)wsb;                 wsb += (size_t)E * 4;
    float* dinv     = (float*)wsb;               wsb += (size_t)N * 4;
    float* s        = (float*)wsb;               wsb += (size_t)N * 4;
    float* agg      = (float*)wsb;               wsb += (size_t)N * 64 * 4;  // layer2 agg, reused for layer3
    float* h2       = (float*)wsb;               wsb += (size_t)N * 128 * 4;
    float* m        = (float*)wsb;               wsb += (size_t)N * 64 * 4;
    float* pooled   = (float*)wsb;               wsb += (size_t)G * 64 * 4;
    float* counts   = (float*)wsb;               wsb += (size_t)G * 4;

    hipMemsetAsync(deg, 0, (size_t)N * sizeof(int), stream);
    hipMemsetAsync(pooled, 0, (size_t)(G * 64 + G) * sizeof(float), stream);

    int tb = 256;
    int NB = (N + SCAN_CHUNK - 1) / SCAN_CHUNK;   // 49 for N=50000 (must be <= 64)
    degi_kernel<<<(E + tb - 1) / tb, tb, 0, stream>>>(dst, deg, E);
    dinv_kernel<<<(N + tb - 1) / tb, tb, 0, stream>>>(deg, dinv, N);
    bsum_kernel<<<NB, 256, 0, stream>>>(deg, bsum, N);
    bscan_kernel<<<1, 64, 0, stream>>>(bsum, NB);
    rscan_kernel<<<NB, 256, 0, stream>>>(deg, bsum, rowstart, cursor, N, NB);
    fill_kernel<<<(E + tb - 1) / tb, tb, 0, stream>>>(src, dst, cursor, csr, E);
    sagg_gather<<<(N + tb - 1) / tb, tb, 0, stream>>>(rowstart, csr, x, dinv, s, N);
    agg1_gather<<<(N + 3) / 4, tb, 0, stream>>>(rowstart, csr, s, dinv, W1, b1, agg, N);
    gemm1<<<(N + 63) / 64, tb, 0, stream>>>(agg, W2, b2, h2, N);
    gemm2<<<(N + 63) / 64, tb, 0, stream>>>(h2, W3, m, N);
    agg3_gather<<<(N + 3) / 4, tb, 0, stream>>>(rowstart, csr, m, dinv, agg, N);
    int pool_waves = (N + POOL_SUB - 1) / POOL_SUB;
    pool_kernel<<<(pool_waves + 3) / 4, tb, 0, stream>>>(agg, b3, batch, pooled, counts, N);
    mlp_kernel<<<G, 64, 0, stream>>>(pooled, counts, l1w, l1b, l2w, l2b, (float*)d_out);
}